// Round 11
// baseline (107.070 us; speedup 1.0000x reference)
//
#include <hip/hip_runtime.h>

// Problem constants: B=4, N=512, M=512, D=128, H=256, DOUT=128
#define BB    4
#define NN    512
#define MM    512
#define DD    128
#define HH    256
#define DOUTC 128

// ============================================================================
// ROUND 11 = COUNTER-VISIBILITY EXPERIMENT. Kernel bodies identical to round
// 10, but each takes `reps` and repeats its (idempotent) work so the dispatch
// exceeds the ~40 us harness fills and surfaces in the rocprof top-5 WITH
// counters. precompute: reps=8 (~8P). fused_main: reps=2 (~2F).
// Split also falls out algebraically: dur11 = 8P + 2F + oh, dur10 = P + F + oh.
// ============================================================================

typedef float v4f __attribute__((ext_vector_type(4)));

__device__ __forceinline__ v4f shfl_xor4(v4f v, int m) {
    v4f r;
    r.x = __shfl_xor(v.x, m, 64);
    r.y = __shfl_xor(v.y, m, 64);
    r.z = __shfl_xor(v.z, m, 64);
    r.w = __shfl_xor(v.w, m, 64);
    return r;
}

// ---------------------------------------------------------------------------
// Kernel 1: precompute — round-10 body wrapped in rep loop
// ---------------------------------------------------------------------------
__global__ __launch_bounds__(1024) void precompute_ac(
    const float* __restrict__ X, const float* __restrict__ Y,
    const float* __restrict__ W1, const float* __restrict__ b1,
    float* __restrict__ AC, int reps)
{
    __shared__ __align__(16) float rows[16][DD];     // 8 KB
    __shared__ __align__(16) v4f mrg[3][4][4][64];   // 48 KB: [dq-1][rs][r][hq]
    const int bid = blockIdx.x;
    const int t   = threadIdx.x;
    const int isC = bid >> 7;
    const int r0  = (bid & 127) * 16;                // global row (b*512+m)
    const float* src = isC ? X : Y;

    if (t < 512)
        reinterpret_cast<v4f*>(&rows[0][0])[t] =
            reinterpret_cast<const v4f*>(src + (size_t)r0 * DD)[t];
    __syncthreads();

    const int hq = t & 63;            // h-quad
    const int dq = (t >> 6) & 3;      // d-chunk (wave-uniform)
    const int rs = t >> 8;            // row-group (wave-uniform)
    const int d0 = dq * 32;
    const float* wp = W1 + (isC ? DD * HH : 0) + hq * 4;

    for (int rep = 0; rep < reps; ++rep) {
        v4f acc[4];
#pragma unroll
        for (int r = 0; r < 4; ++r) acc[r] = (v4f){0.f, 0.f, 0.f, 0.f};

#pragma unroll 2
        for (int dg = 0; dg < 32; dg += 4) {
            const int d = d0 + dg;
            const v4f w0 = *reinterpret_cast<const v4f*>(&wp[(d + 0) * HH]);
            const v4f w1 = *reinterpret_cast<const v4f*>(&wp[(d + 1) * HH]);
            const v4f w2 = *reinterpret_cast<const v4f*>(&wp[(d + 2) * HH]);
            const v4f w3 = *reinterpret_cast<const v4f*>(&wp[(d + 3) * HH]);
#pragma unroll
            for (int r = 0; r < 4; ++r) {
                const v4f rv = *reinterpret_cast<const v4f*>(&rows[rs * 4 + r][d]);
                acc[r] += w0 * rv.x;
                acc[r] += w1 * rv.y;
                acc[r] += w2 * rv.z;
                acc[r] += w3 * rv.w;
            }
        }

        if (dq > 0) {
#pragma unroll
            for (int r = 0; r < 4; ++r) mrg[dq - 1][rs][r][hq] = acc[r];
        }
        __syncthreads();
        if (dq == 0) {
#pragma unroll
            for (int r = 0; r < 4; ++r) {
#pragma unroll
                for (int p = 0; p < 3; ++p) acc[r] += mrg[p][rs][r][hq];
            }
            v4f bias = (v4f){0.f, 0.f, 0.f, 0.f};
            if (isC) bias = *reinterpret_cast<const v4f*>(&b1[hq * 4]);
#pragma unroll
            for (int r = 0; r < 4; ++r)
                *reinterpret_cast<v4f*>(
                    &AC[((size_t)(isC * 2048 + r0 + rs * 4 + r)) * HH + hq * 4]) =
                    acc[r] + bias;
        }
        __syncthreads();   // WAR on mrg before next rep
    }
}

// ---------------------------------------------------------------------------
// Kernel 2: fused abs-sum + W2 epilogue — round-10 body wrapped in rep loop
// ---------------------------------------------------------------------------
__global__ __launch_bounds__(1024) void fused_main(
    const float* __restrict__ A, const float* __restrict__ C,
    const float* __restrict__ W2, const float* __restrict__ b2,
    float* __restrict__ out, int reps)
{
    __shared__ __align__(16) v4f scratch[1536];     // 24 KB: qm-partials / red
    __shared__ __align__(16) v4f satp[3][4][16];    // 3 KB
    __shared__ __align__(16) float S[8][HH];        // 8 KB
    const int bid = blockIdx.x;
    const int b   = (bid & 7) >> 1;                          // XCD-pair -> batch
    const int n0  = ((((bid >> 3) << 1) | (bid & 1))) * 8;   // n-tile
    const int t   = threadIdx.x;

    const int w    = t >> 6;
    const int l    = t & 63;
    const int hg   = w & 3;
    const int qm   = w >> 2;
    const int hq   = l & 15;
    const int msub = l >> 4;
    const int h0   = hg * 64 + hq * 4;

    const float* Cb = C + ((size_t)(b * NN + n0)) * HH + h0;
    v4f c[8];
#pragma unroll
    for (int j = 0; j < 8; ++j)
        c[j] = *reinterpret_cast<const v4f*>(&Cb[(size_t)j * HH]);

    for (int rep = 0; rep < reps; ++rep) {
        v4f acc[8], sat = (v4f){0.f, 0.f, 0.f, 0.f};
#pragma unroll
        for (int j = 0; j < 8; ++j) acc[j] = (v4f){0.f, 0.f, 0.f, 0.f};

        // m = qm*128 + i*4 + msub, i = 0..31
        const float* Ab = A + ((size_t)(b * MM + qm * 128 + msub)) * HH + h0;
#pragma unroll 4
        for (int i = 0; i < 32; ++i) {
            const v4f a = *reinterpret_cast<const v4f*>(&Ab[(size_t)i * 4 * HH]);
            sat += a;
#pragma unroll
            for (int j = 0; j < 8; ++j) {
                const v4f s = a + c[j];
                acc[j].x += fabsf(s.x);
                acc[j].y += fabsf(s.y);
                acc[j].z += fabsf(s.z);
                acc[j].w += fabsf(s.w);
            }
        }

        // reduce msub (in-register butterfly over lane bits 4,5)
#pragma unroll
        for (int mask = 16; mask <= 32; mask <<= 1) {
#pragma unroll
            for (int j = 0; j < 8; ++j) acc[j] += shfl_xor4(acc[j], mask);
            sat += shfl_xor4(sat, mask);
        }

        // reduce qm via LDS (plain writes, no atomics)
        if (qm > 0 && l < 16) {
#pragma unroll
            for (int j = 0; j < 8; ++j)
                scratch[(((qm - 1) * 4 + hg) * 8 + j) * 16 + l] = acc[j];
            satp[qm - 1][hg][l] = sat;
        }
        __syncthreads();

        if (qm == 0 && l < 16) {
#pragma unroll
            for (int p = 0; p < 3; ++p) {
#pragma unroll
                for (int j = 0; j < 8; ++j)
                    acc[j] += scratch[((p * 4 + hg) * 8 + j) * 16 + l];
                sat += satp[p][hg][l];
            }
#pragma unroll
            for (int j = 0; j < 8; ++j) {
                const v4f sv = 0.5f * (sat + 512.f * c[j] + acc[j]);
                *reinterpret_cast<v4f*>(&S[j][h0]) = sv;
            }
        }
        __syncthreads();

        // phase C: out = S*W2 + 512*b2, k split 4 ways
        const int o0 = (t & 31) * 4;
        const int r  = (t >> 5) & 7;
        const int kq = t >> 8;
        const int k0 = kq * 64;
        v4f a4 = (v4f){0.f, 0.f, 0.f, 0.f};
        const float* w2p = W2 + o0;
#pragma unroll 4
        for (int k = k0; k < k0 + 64; k += 4) {
            const v4f sv = *reinterpret_cast<const v4f*>(&S[r][k]);   // broadcast
            const v4f wA = *reinterpret_cast<const v4f*>(&w2p[(k + 0) * DOUTC]);
            const v4f wB = *reinterpret_cast<const v4f*>(&w2p[(k + 1) * DOUTC]);
            const v4f wC = *reinterpret_cast<const v4f*>(&w2p[(k + 2) * DOUTC]);
            const v4f wD = *reinterpret_cast<const v4f*>(&w2p[(k + 3) * DOUTC]);
            a4 += wA * sv.x;
            a4 += wB * sv.y;
            a4 += wC * sv.z;
            a4 += wD * sv.w;
        }
        if (kq) scratch[(kq - 1) * 256 + (t & 255)] = a4;
        __syncthreads();
        if (kq == 0) {
#pragma unroll
            for (int p = 0; p < 3; ++p) a4 += scratch[p * 256 + t];
            a4 += 512.f * (*reinterpret_cast<const v4f*>(&b2[o0]));
            *reinterpret_cast<v4f*>(&out[((size_t)(b * NN + n0 + r)) * DOUTC + o0]) = a4;
        }
        __syncthreads();   // WAR on scratch before next rep
    }
}

// ---------------------------------------------------------------------------
extern "C" void kernel_launch(void* const* d_in, const int* in_sizes, int n_in,
                              void* d_out, int out_size, void* d_ws, size_t ws_size,
                              hipStream_t stream) {
    const float* X  = (const float*)d_in[0];
    const float* Y  = (const float*)d_in[1];
    const float* W1 = (const float*)d_in[2];
    const float* b1 = (const float*)d_in[3];
    const float* W2 = (const float*)d_in[4];
    const float* b2 = (const float*)d_in[5];
    float* out = (float*)d_out;

    float* AC = (float*)d_ws;        // 4 MB: A rows 0..2047, C rows 2048..4095
    float* A  = AC;
    float* Cm = AC + 2048 * HH;

    hipLaunchKernelGGL(precompute_ac, dim3(256), dim3(1024), 0, stream,
                       X, Y, W1, b1, AC, 8);
    hipLaunchKernelGGL(fused_main, dim3(256), dim3(1024), 0, stream,
                       A, Cm, W2, b2, out, 2);
}

// Round 12
// 42.294 us; speedup vs baseline: 2.5315x; 2.5315x over previous
//
#include <hip/hip_runtime.h>

// Problem constants: B=4, N=512, M=512, D=128, H=256, DOUT=128
#define BB    4
#define NN    512
#define MM    512
#define DD    128
#define HH    256
#define DOUTC 128

typedef float v2f __attribute__((ext_vector_type(2)));
typedef float v4f __attribute__((ext_vector_type(4)));

// ---------------------------------------------------------------------------
// Kernel 1: precompute (256 blocks x 1024 threads, 16 rows/block) — round-10
// version, measured 4.2 us. R=4 register tiling, one plain-LDS dq merge.
// ---------------------------------------------------------------------------
__global__ __launch_bounds__(1024) void precompute_ac(
    const float* __restrict__ X, const float* __restrict__ Y,
    const float* __restrict__ W1, const float* __restrict__ b1,
    float* __restrict__ AC)
{
    __shared__ __align__(16) float rows[16][DD];     // 8 KB
    __shared__ __align__(16) v4f mrg[3][4][4][64];   // 48 KB: [dq-1][rs][r][hq]
    const int bid = blockIdx.x;
    const int t   = threadIdx.x;
    const int isC = bid >> 7;
    const int r0  = (bid & 127) * 16;                // global row (b*512+m)
    const float* src = isC ? X : Y;

    if (t < 512)
        reinterpret_cast<v4f*>(&rows[0][0])[t] =
            reinterpret_cast<const v4f*>(src + (size_t)r0 * DD)[t];
    __syncthreads();

    const int hq = t & 63;            // h-quad
    const int dq = (t >> 6) & 3;      // d-chunk (wave-uniform)
    const int rs = t >> 8;            // row-group (wave-uniform)
    const int d0 = dq * 32;
    const float* wp = W1 + (isC ? DD * HH : 0) + hq * 4;

    v4f acc[4];
#pragma unroll
    for (int r = 0; r < 4; ++r) acc[r] = (v4f){0.f, 0.f, 0.f, 0.f};

#pragma unroll 2
    for (int dg = 0; dg < 32; dg += 4) {
        const int d = d0 + dg;
        const v4f w0 = *reinterpret_cast<const v4f*>(&wp[(d + 0) * HH]);
        const v4f w1 = *reinterpret_cast<const v4f*>(&wp[(d + 1) * HH]);
        const v4f w2 = *reinterpret_cast<const v4f*>(&wp[(d + 2) * HH]);
        const v4f w3 = *reinterpret_cast<const v4f*>(&wp[(d + 3) * HH]);
#pragma unroll
        for (int r = 0; r < 4; ++r) {
            const v4f rv = *reinterpret_cast<const v4f*>(&rows[rs * 4 + r][d]);
            acc[r] += w0 * rv.x;
            acc[r] += w1 * rv.y;
            acc[r] += w2 * rv.z;
            acc[r] += w3 * rv.w;
        }
    }

    if (dq > 0) {
#pragma unroll
        for (int r = 0; r < 4; ++r) mrg[dq - 1][rs][r][hq] = acc[r];
    }
    __syncthreads();
    if (dq == 0) {
#pragma unroll
        for (int r = 0; r < 4; ++r) {
#pragma unroll
            for (int p = 0; p < 3; ++p) acc[r] += mrg[p][rs][r][hq];
        }
        v4f bias = (v4f){0.f, 0.f, 0.f, 0.f};
        if (isC) bias = *reinterpret_cast<const v4f*>(&b1[hq * 4]);
#pragma unroll
        for (int r = 0; r < 4; ++r)
            *reinterpret_cast<v4f*>(
                &AC[((size_t)(isC * 2048 + r0 + rs * 4 + r)) * HH + hq * 4]) =
                acc[r] + bias;
    }
}

// ---------------------------------------------------------------------------
// Kernel 2: fused abs-sum + W2 epilogue — ROUND-12 RESTRUCTURE.
// 512 blocks x 512 threads (2 blocks/CU). Block = (b = bid>>7, 4 n-rows).
// Lane l = t&63 covers the FULL h-range (4 h each, 256 = H): wave loads of A
// are perfectly coalesced 1 KB and NO intra-wave reduce is needed (round-11
// counters showed the shfl butterfly + 1-block/CU grid cost ~20 us).
// Wave qm = t>>6 owns 64 m. relu(x) = (x+|x|)/2. v2f ops -> v_pk_add_f32.
//   phase A: acc[4 rows] = sum_m |A+C|, sat = sum_m A   (per 64-m chunk)
//   merge:   all 8 waves write partials to LDS; waves 0-3 finish row r=qm
//   phase C: out = S*W2 + 512*b2 (k split 4 ways, LDS reduce)
// ---------------------------------------------------------------------------
__global__ __launch_bounds__(512) void fused_main(
    const float* __restrict__ A, const float* __restrict__ C,
    const float* __restrict__ W2, const float* __restrict__ b2,
    float* __restrict__ out)
{
    __shared__ __align__(16) v4f mergeA[8][4][64];   // 32 KB [qm][r][l]
    __shared__ __align__(16) v4f mergeS[8][64];      // 8 KB  [qm][l]
    __shared__ __align__(16) float S[4][HH];         // 4 KB
    const int bid = blockIdx.x;
    const int b   = bid >> 7;
    const int n0  = (bid & 127) * 4;
    const int t   = threadIdx.x;
    const int l   = t & 63;
    const int qm  = t >> 6;            // wave-uniform m-chunk (64 m)
    const int h0  = l * 4;

    // C rows for this thread's 4 h at the block's 4 n-rows
    const float* Cb = C + ((size_t)(b * NN + n0)) * HH + h0;
    v4f c4[4];
#pragma unroll
    for (int j = 0; j < 4; ++j)
        c4[j] = *reinterpret_cast<const v4f*>(&Cb[(size_t)j * HH]);
    v2f c01[4], c23[4];
#pragma unroll
    for (int j = 0; j < 4; ++j) {
        c01[j] = (v2f){c4[j].x, c4[j].y};
        c23[j] = (v2f){c4[j].z, c4[j].w};
    }

    float acc[4][4];
#pragma unroll
    for (int j = 0; j < 4; ++j)
#pragma unroll
        for (int u = 0; u < 4; ++u) acc[j][u] = 0.f;
    v2f sat01 = (v2f){0.f, 0.f}, sat23 = (v2f){0.f, 0.f};

    const float* Ab = A + ((size_t)(b * MM + qm * 64)) * HH + h0;
#pragma unroll 4
    for (int m = 0; m < 64; ++m) {
        const v4f a = *reinterpret_cast<const v4f*>(&Ab[(size_t)m * HH]);
        const v2f a01 = (v2f){a.x, a.y};
        const v2f a23 = (v2f){a.z, a.w};
        sat01 += a01;                         // v_pk_add_f32
        sat23 += a23;
#pragma unroll
        for (int j = 0; j < 4; ++j) {
            const v2f s01 = a01 + c01[j];     // v_pk_add_f32
            const v2f s23 = a23 + c23[j];
            acc[j][0] += fabsf(s01.x);        // v_add_f32 acc, |s|, acc
            acc[j][1] += fabsf(s01.y);
            acc[j][2] += fabsf(s23.x);
            acc[j][3] += fabsf(s23.y);
        }
    }

    // ---- merge 8 qm-partials via plain LDS writes ----
#pragma unroll
    for (int j = 0; j < 4; ++j)
        mergeA[qm][j][l] = (v4f){acc[j][0], acc[j][1], acc[j][2], acc[j][3]};
    mergeS[qm][l] = (v4f){sat01.x, sat01.y, sat23.x, sat23.y};
    __syncthreads();

    // waves 0-3: finish row r = qm
    if (qm < 4) {
        const int r = qm;
        v4f sum = mergeA[0][r][l];
#pragma unroll
        for (int p = 1; p < 8; ++p) sum += mergeA[p][r][l];
        v4f st = mergeS[0][l];
#pragma unroll
        for (int p = 1; p < 8; ++p) st += mergeS[p][l];
        const v4f sval = 0.5f * (st + 512.f * c4[r] + sum);
        *reinterpret_cast<v4f*>(&S[r][h0]) = sval;
    }
    __syncthreads();

    // ---- phase C: out = S*W2 + 512*b2, k split 4 ways ----
    const int o0 = (t & 31) * 4;       // 128 o
    const int r  = (t >> 5) & 3;       // 4 rows
    const int kq = t >> 7;             // 4 k-quarters of 64
    const int k0 = kq * 64;
    v4f a4 = (v4f){0.f, 0.f, 0.f, 0.f};
    const float* w2p = W2 + o0;
#pragma unroll 4
    for (int k = k0; k < k0 + 64; k += 4) {
        const v4f sv = *reinterpret_cast<const v4f*>(&S[r][k]);   // broadcast
        const v4f wA = *reinterpret_cast<const v4f*>(&w2p[(k + 0) * DOUTC]);
        const v4f wB = *reinterpret_cast<const v4f*>(&w2p[(k + 1) * DOUTC]);
        const v4f wC = *reinterpret_cast<const v4f*>(&w2p[(k + 2) * DOUTC]);
        const v4f wD = *reinterpret_cast<const v4f*>(&w2p[(k + 3) * DOUTC]);
        a4 += wA * sv.x;
        a4 += wB * sv.y;
        a4 += wC * sv.z;
        a4 += wD * sv.w;
    }
    v4f* red = reinterpret_cast<v4f*>(&mergeA[0][0][0]);   // reuse 6 KB
    if (kq) red[(kq - 1) * 128 + (t & 127)] = a4;
    __syncthreads();
    if (kq == 0) {
#pragma unroll
        for (int p = 0; p < 3; ++p) a4 += red[p * 128 + (t & 127)];
        a4 += 512.f * (*reinterpret_cast<const v4f*>(&b2[o0]));
        *reinterpret_cast<v4f*>(&out[((size_t)(b * NN + n0 + r)) * DOUTC + o0]) = a4;
    }
}

// ---------------------------------------------------------------------------
extern "C" void kernel_launch(void* const* d_in, const int* in_sizes, int n_in,
                              void* d_out, int out_size, void* d_ws, size_t ws_size,
                              hipStream_t stream) {
    const float* X  = (const float*)d_in[0];
    const float* Y  = (const float*)d_in[1];
    const float* W1 = (const float*)d_in[2];
    const float* b1 = (const float*)d_in[3];
    const float* W2 = (const float*)d_in[4];
    const float* b2 = (const float*)d_in[5];
    float* out = (float*)d_out;

    float* AC = (float*)d_ws;        // 4 MB: A rows 0..2047, C rows 2048..4095
    float* A  = AC;
    float* Cm = AC + 2048 * HH;

    hipLaunchKernelGGL(precompute_ac, dim3(256), dim3(1024), 0, stream,
                       X, Y, W1, b1, AC);
    hipLaunchKernelGGL(fused_main, dim3(512), dim3(512), 0, stream,
                       A, Cm, W2, b2, out);
}